// Round 4
// baseline (192.315 us; speedup 1.0000x reference)
//
#include <hip/hip_runtime.h>
#include <cstdint>

// VectorQuantizer: x[16,1024,16,16] f32, codebook[1,8192,1024], values[1,8192,1024]
// Round 11 == Round 9 (four desk audits; GPU broker down all session): 256x256-
// tile i8 dist GEMM, 8 waves, double-buffered LDS 128 KB, counted-vmcnt schedule
// (steady-state s_waitcnt vmcnt(8), peeled drain 8->4->0), raw s_barrier +
// sched_barrier(0) pin, setprio(1) around the MFMA cluster (T3+T4+T5 stack).
// Screening is i8 (s=24, exact integer dot); exact fp32 rescore of top-4.

constexpr int Dd = 1024;   // feature dim (GEMM K)
constexpr int Nn = 256;    // tokens per batch
constexpr int Bb = 16;     // batch
constexpr int Kk = 8192;   // codes (GEMM N)
constexpr int Mm = 4096;   // tokens (GEMM M)
constexpr int STAGES = Dd / 64;     // 16 x 64B K-chunks (kb index)
constexpr int NITER = STAGES / 2;   // 8 main-loop iterations, 128B K per iter
constexpr int NCHUNK = Kk / 64;     // 128 chunks of 64 codes
constexpr int NCAND = NCHUNK * 2;   // 256 candidates per token
constexpr float QS = 24.0f;         // quant scale
constexpr float SC2 = 2.0f / (QS * QS);

typedef __attribute__((ext_vector_type(4))) int vi4;       // 16 i8 = 4 VGPRs
typedef unsigned long long u64;
typedef unsigned char uchar;

__device__ __forceinline__ void gload16(const void* g, void* l) {
    // async global->LDS; lds dest = wave-uniform base + lane*16 (verified r2-r5)
    __builtin_amdgcn_global_load_lds((const __attribute__((address_space(1))) uint32_t*)g,
                                     (__attribute__((address_space(3))) uint32_t*)l, 16, 0, 0);
}

__device__ __forceinline__ void mm2(u64& a, u64& b) {  // sort pair ascending
    u64 lo = a < b ? a : b;
    u64 hi = a < b ? b : a;
    a = lo; b = hi;
}
// merge sorted pairs: (a1,a2) <- top-2 of {a1,a2,b1,b2}
__device__ __forceinline__ void merge2(u64& a1, u64& a2, u64 b1, u64 b2) {
    u64 t1 = a1 < b1 ? a1 : b1;
    u64 hi = a1 < b1 ? b1 : a1;
    u64 l2 = a2 < b2 ? a2 : b2;
    a2 = hi < l2 ? hi : l2;
    a1 = t1;
}

__device__ __forceinline__ int q8(float v) {  // round-to-nearest, clamp [-127,127]
    int qi = (int)rintf(v * QS);
    qi = qi > 127 ? 127 : (qi < -127 ? -127 : qi);
    return qi & 0xFF;
}
__device__ __forceinline__ int pk4i(float a, float b, float c, float d) {
    return q8(a) | (q8(b) << 8) | (q8(c) << 16) | (q8(d) << 24);
}

// Fragment-order packed layout (A and B identical; verified-symmetric for the
// 16x16 family): P[(g*16 + kb)*64 + lane]*16B, g = row>>4, kb = k>>6,
// lane = (row&15) | (q<<4), q = (k>>4)&3, byte j = k&15.

// ---------- prep ----------
// grid: [0,512) cb->Bpk + esq; [512,1024) x->Apk; [1024,1536) x->xT (bigws only)
__global__ __launch_bounds__(256) void prep_kernel(const float* __restrict__ x,
                                                   const float* __restrict__ cb,
                                                   uchar* __restrict__ Apk,
                                                   uchar* __restrict__ Bpk,
                                                   float* __restrict__ esq,
                                                   float* __restrict__ xT) {
    const int tid = threadIdx.x;
    if (blockIdx.x < 512) {  // codebook: 16 codes/block; thread=(rl 4b hi, seg 4b lo)
        const int rl = tid >> 4, seg = tid & 15;   // seg == kb
        const int code = blockIdx.x * 16 + rl;
        const float* src = cb + (size_t)code * Dd + seg * 64;
        float v[64];
        float ss = 0.f;
#pragma unroll
        for (int j = 0; j < 64; j += 4) {
            float4 f = *(const float4*)&src[j];
            v[j] = f.x; v[j + 1] = f.y; v[j + 2] = f.z; v[j + 3] = f.w;
            ss += f.x * f.x + f.y * f.y + f.z * f.z + f.w * f.w;
        }
#pragma unroll
        for (int off = 8; off; off >>= 1) ss += __shfl_down(ss, off, 16);
        if (seg == 0) esq[code] = ss;
        const int g = code >> 4, rlane = code & 15;
#pragma unroll
        for (int q = 0; q < 4; ++q) {
            int o[4];
#pragma unroll
            for (int w4 = 0; w4 < 4; ++w4) {
                const int j = q * 16 + w4 * 4;
                o[w4] = pk4i(v[j], v[j + 1], v[j + 2], v[j + 3]);
            }
            *(uint4*)&Bpk[((size_t)(g * 16 + seg) * 64 + (rlane | (q << 4))) * 16] =
                *(const uint4*)o;
        }
    } else if (blockIdx.x < 1024) {  // x -> Apk: block=(b, d-chunk of 32), thread=n
        const int bb = blockIdx.x - 512;
        const int b = bb >> 5, d0 = (bb & 31) * 32, n = tid;
        const int t = b * 256 + n;
        const float* xb = x + (size_t)b * Dd * Nn + n;
        const int g = t >> 4, rlane = t & 15, kb = d0 >> 6, qbase = (d0 & 32) >> 4;
        float v[32];
#pragma unroll
        for (int jj = 0; jj < 32; ++jj) v[jj] = xb[(size_t)(d0 + jj) * Nn];
#pragma unroll
        for (int h = 0; h < 2; ++h) {
            int o[4];
#pragma unroll
            for (int w4 = 0; w4 < 4; ++w4) {
                const int j = h * 16 + w4 * 4;
                o[w4] = pk4i(v[j], v[j + 1], v[j + 2], v[j + 3]);
            }
            *(uint4*)&Apk[((size_t)(g * 16 + kb) * 64 + (rlane | ((qbase + h) << 4))) * 16] =
                *(const uint4*)o;
        }
    } else {  // x -> xT fp32 (only when xT doesn't alias Apk/Bpk)
        const int bb = blockIdx.x - 1024;
        const int b = bb >> 5, d0 = (bb & 31) * 32, n = tid;
        const float* xb = x + (size_t)b * Dd * Nn + n;
        float* row = xT + (size_t)(b * Nn + n) * Dd + d0;
#pragma unroll
        for (int jj = 0; jj < 8; ++jj) {
            float4 v;
            v.x = xb[(size_t)(d0 + jj * 4 + 0) * Nn];
            v.y = xb[(size_t)(d0 + jj * 4 + 1) * Nn];
            v.z = xb[(size_t)(d0 + jj * 4 + 2) * Nn];
            v.w = xb[(size_t)(d0 + jj * 4 + 3) * Nn];
            *(float4*)&row[jj * 4] = v;
        }
    }
}

// ---------- x -> xT fp32 (fallback path, AFTER dist; aliases Apk/Bpk region) ----------
__global__ __launch_bounds__(256) void transx_kernel(const float* __restrict__ x,
                                                     float* __restrict__ xT) {
    const int n = threadIdx.x, b = blockIdx.x, d0 = blockIdx.y * 32;
    const float* xb = x + (size_t)b * Dd * Nn + n;
    float* row = xT + (size_t)(b * Nn + n) * Dd + d0;
#pragma unroll
    for (int jj = 0; jj < 8; ++jj) {
        float4 v;
        v.x = xb[(size_t)(d0 + jj * 4 + 0) * Nn];
        v.y = xb[(size_t)(d0 + jj * 4 + 1) * Nn];
        v.z = xb[(size_t)(d0 + jj * 4 + 2) * Nn];
        v.w = xb[(size_t)(d0 + jj * 4 + 3) * Nn];
        *(float4*)&row[jj * 4] = v;
    }
}

// ---------- i8 MFMA distance: 256x256 tile, counted-vmcnt phase schedule ----------
// grid (32, 16), 512 threads = 8 waves (wm in [0,2), wn in [0,4)).
// Wave owns a 128x64 output tile = 8x4 fragments of 16x16x64 MFMA.
// LDS: double buffer x 2 K-tiles(64B) x 16 groups x 1KB for A and for B = 128 KB.
// Main loop (7 iters, 128B K each) runs 2 phases; each phase:
//   issue 4 global_load_lds for iter i+1 -> s_waitcnt vmcnt(8) -> s_barrier ->
//   sched_barrier(0) -> 12 ds_read_b128 + 32 MFMA under setprio(1).
// vmcnt invariant: at each steady-state wait, outstanding == 12 and the 4 oldest
// are exactly the loads published by this phase's barrier (8 newer in flight).
// Last iteration peeled: no prefetch, drains vmcnt 8->4->0, so the kernel never
// ends with outstanding LDS-DMA. WAR on buffers: readers of a cell finish (their
// lgkmcnt is consumed pre-MFMA) before the barrier that precedes the overwrite.
__global__ __launch_bounds__(512, 2) void mfma_dist_kernel(const uchar* __restrict__ Apk,
                                                           const uchar* __restrict__ Bpk,
                                                           const float* __restrict__ esq,
                                                           u64* __restrict__ cand) {
    __shared__ uchar As[2 * 2 * 16 * 1024];  // [buf][kt][group][1KB]
    __shared__ uchar Bs[2 * 2 * 16 * 1024];

    const int tid = threadIdx.x, lane = tid & 63, w = tid >> 6;
    const int wm = w >> 2, wn = w & 3;
    const int nBase = blockIdx.x * 256, mBase = blockIdx.y * 256;
    const int gA = blockIdx.y * 16, gB = blockIdx.x * 16;  // global 16-row group bases

    vi4 acc[8][4];
#pragma unroll
    for (int i = 0; i < 8; ++i)
#pragma unroll
        for (int j = 0; j < 4; ++j) acc[i][j] = (vi4)0;

    // Staging assignment: waves 0-3 stage A groups (w&3)*4..+3, waves 4-7 stage B.
    const uchar* gmat = (w < 4) ? Apk : Bpk;
    const int gBase = ((w < 4) ? gA : gB) + (w & 3) * 4;
    const uchar* gsrc = gmat + (size_t)gBase * 16384 + (size_t)lane * 16;
    uchar* swave = ((w < 4) ? As : Bs) + (w & 3) * 4096;  // + buf*32768 + kt*16384 + r*1024

    auto compute = [&](int buf, int kt) {
        __builtin_amdgcn_s_setprio(1);
        const uchar* ab = As + buf * 32768 + kt * 16384;
        const uchar* bb = Bs + buf * 32768 + kt * 16384;
        vi4 af[8], bf[4];
#pragma unroll
        for (int mi = 0; mi < 8; ++mi)
            af[mi] = *(const vi4*)&ab[((wm * 8 + mi) * 64 + lane) * 16];
#pragma unroll
        for (int ni = 0; ni < 4; ++ni)
            bf[ni] = *(const vi4*)&bb[((wn * 4 + ni) * 64 + lane) * 16];
#pragma unroll
        for (int mi = 0; mi < 8; ++mi)
#pragma unroll
            for (int ni = 0; ni < 4; ++ni)
                acc[mi][ni] = __builtin_amdgcn_mfma_i32_16x16x64_i8(
                    af[mi], bf[ni], acc[mi][ni], 0, 0, 0);
        __builtin_amdgcn_s_setprio(0);
    };

    // prologue: stage iter 0 (kb = 0 for kt0, kb = 1 for kt1) into buf 0
#pragma unroll
    for (int kt = 0; kt < 2; ++kt)
#pragma unroll
        for (int r = 0; r < 4; ++r)
            gload16(gsrc + (size_t)(r * 16 + kt) * 1024, swave + kt * 16384 + r * 1024);

    for (int i = 0; i < NITER - 1; ++i) {
        const int buf = i & 1;
#pragma unroll
        for (int kt = 0; kt < 2; ++kt) {
            // issue next-iter loads for this kt into buf^1
            const int kbn = 2 * i + 2 + kt;
            uchar* ldst = swave + (buf ^ 1) * 32768 + kt * 16384;
#pragma unroll
            for (int r = 0; r < 4; ++r)
                gload16(gsrc + (size_t)(r * 16 + kbn) * 1024, ldst + r * 1024);

            asm volatile("s_waitcnt vmcnt(8)" ::: "memory");  // publish iter i, kt
            __builtin_amdgcn_s_barrier();
            __builtin_amdgcn_sched_barrier(0);  // pin ds_reads behind the barrier
            compute(buf, kt);
        }
    }
    // peeled last iteration (buf = 1): no prefetch, explicit drain 8 -> 4 -> 0
    asm volatile("s_waitcnt vmcnt(4)" ::: "memory");
    __builtin_amdgcn_s_barrier();
    __builtin_amdgcn_sched_barrier(0);
    compute(1, 0);
    asm volatile("s_waitcnt vmcnt(0)" ::: "memory");
    __builtin_amdgcn_s_barrier();
    __builtin_amdgcn_sched_barrier(0);
    compute(1, 1);

    // Epilogue (verified r3 structure). C/D: col = lane&15 (+ni*16),
    // row = (lane>>4)*4 + reg. score = max(esq - (2/s^2)*dot, 0) -> raw-bit keys.
    const int chunk = blockIdx.x * 4 + wn;
    uint32_t colc[4];
    float e4[4];
#pragma unroll
    for (int ni = 0; ni < 4; ++ni) {
        colc[ni] = (uint32_t)(nBase + wn * 64 + ni * 16 + (lane & 15));
        e4[ni] = esq[colc[ni]];
    }
#pragma unroll
    for (int mi = 0; mi < 8; ++mi) {
#pragma unroll
        for (int reg = 0; reg < 4; ++reg) {
            u64 p[4];
#pragma unroll
            for (int ni = 0; ni < 4; ++ni) {
                float s = fmaxf(fmaf(-SC2, (float)acc[mi][ni][reg], e4[ni]), 0.f);
                p[ni] = ((u64)__float_as_uint(s) << 32) | colc[ni];
            }
            mm2(p[0], p[1]); mm2(p[2], p[3]);
            merge2(p[0], p[1], p[2], p[3]);
            u64 t1 = p[0], t2 = p[1];
#pragma unroll
            for (int d = 1; d < 16; d <<= 1) {
                u64 o1 = __shfl_xor(t1, d, 64);
                u64 o2 = __shfl_xor(t2, d, 64);
                merge2(t1, t2, o1, o2);
            }
            if ((lane & 15) == 0) {
                const int t = mBase + wm * 128 + mi * 16 + (lane >> 4) * 4 + reg;
                cand[(size_t)t * NCAND + chunk * 2 + 0] = t1;
                cand[(size_t)t * NCAND + chunk * 2 + 1] = t2;
            }
        }
    }
}

// ---------- fused select(top-4 of 256) + exact fp32 rescore ----------
__global__ __launch_bounds__(256) void selres_kernel(const u64* __restrict__ cand,
                                                     const float* __restrict__ xT,
                                                     const float* __restrict__ cb,
                                                     const float* __restrict__ esq,
                                                     int* __restrict__ fidx) {
    __shared__ u64 wtop[4][4];
    __shared__ int cs[4];
    __shared__ float red[4][4];
    const int t = blockIdx.x, tid = threadIdx.x, lane = tid & 63, w = tid >> 6;
    u64 v = cand[(size_t)t * NCAND + tid];
#pragma unroll
    for (int rd = 0; rd < 4; ++rd) {  // per-wave top-4
        u64 m = v;
#pragma unroll
        for (int d = 32; d; d >>= 1) {
            u64 o = __shfl_xor(m, d, 64);
            m = m < o ? m : o;
        }
        if (lane == 0) wtop[w][rd] = m;
        if (v == m) v = ~0ULL;  // packed keys unique per token
    }
    __syncthreads();
    if (tid == 0) {  // merge 16 -> global top-4
        u64 a[16];
#pragma unroll
        for (int i = 0; i < 16; ++i) a[i] = wtop[i >> 2][i & 3];
#pragma unroll
        for (int rd = 0; rd < 4; ++rd) {
            int bi = 0;
            u64 m = a[0];
#pragma unroll
            for (int i = 1; i < 16; ++i)
                if (a[i] < m) { m = a[i]; bi = i; }
            cs[rd] = (int)(uint32_t)m;
            a[bi] = ~0ULL;
        }
    }
    __syncthreads();
    int c[4];
#pragma unroll
    for (int j = 0; j < 4; ++j) c[j] = cs[j];
    float4 xv = *(const float4*)&xT[(size_t)t * Dd + tid * 4];
    float part[4];
#pragma unroll
    for (int cc = 0; cc < 4; ++cc) {
        float4 wv = *(const float4*)&cb[(size_t)c[cc] * Dd + tid * 4];
        part[cc] = xv.x * wv.x + xv.y * wv.y + xv.z * wv.z + xv.w * wv.w;
    }
#pragma unroll
    for (int cc = 0; cc < 4; ++cc)
#pragma unroll
        for (int off = 32; off; off >>= 1) part[cc] += __shfl_down(part[cc], off, 64);
    if ((tid & 63) == 0)
#pragma unroll
        for (int cc = 0; cc < 4; ++cc) red[tid >> 6][cc] = part[cc];
    __syncthreads();
    if (tid == 0) {
        float bs = 1e30f;
        int bi = 0x7FFFFFFF;
#pragma unroll
        for (int cc = 0; cc < 4; ++cc) {
            float cross = red[0][cc] + red[1][cc] + red[2][cc] + red[3][cc];
            float s = fmaf(-2.f, cross, esq[c[cc]]);
            if (s < bs || (s == bs && c[cc] < bi)) { bs = s; bi = c[cc]; }
        }
        fidx[t] = bi;
    }
}

// ---------- gather values -> out ----------
__global__ __launch_bounds__(256) void gather_kernel(const int* __restrict__ fidx,
                                                     const float* __restrict__ values,
                                                     float* __restrict__ out) {
    const int n = threadIdx.x, b = blockIdx.x, dc = blockIdx.y;
    const int row = fidx[b * Nn + n];
    const float* src = values + (size_t)row * Dd + dc * 64;
    float* dst = out + (size_t)b * Dd * Nn + (size_t)dc * 64 * Nn + n;
#pragma unroll
    for (int j = 0; j < 64; j += 4) {
        float4 v = *(const float4*)(src + j);
        dst[(j + 0) * Nn] = v.x;
        dst[(j + 1) * Nn] = v.y;
        dst[(j + 2) * Nn] = v.z;
        dst[(j + 3) * Nn] = v.w;
    }
}

extern "C" void kernel_launch(void* const* d_in, const int* in_sizes, int n_in,
                              void* d_out, int out_size, void* d_ws, size_t ws_size,
                              hipStream_t stream) {
    const float* x = (const float*)d_in[0];
    const float* cb = (const float*)d_in[1];
    const float* vals = (const float*)d_in[2];
    float* out = (float*)d_out;

    // ws: [Apk 4M][Bpk 8M][pad->16M][esq 32K][cand 8M][fidx 16K] = 24.28 MB.
    // bigws: xT gets its own 16 MB after that (40.3 MB) and prep fills it;
    // else xT aliases the first 16 MB and is filled post-dist by transx.
    char* p = (char*)d_ws;
    uchar* Apk = (uchar*)p;
    uchar* Bpk = (uchar*)(p + ((size_t)4 << 20));
    float* esq = (float*)(p + ((size_t)16 << 20));
    u64* cand = (u64*)(p + ((size_t)16 << 20) + Kk * 4);
    int* fidx = (int*)(p + ((size_t)16 << 20) + Kk * 4 + (size_t)Mm * NCAND * 8);
    const size_t base = ((size_t)16 << 20) + Kk * 4 + (size_t)Mm * NCAND * 8 + Mm * 4;
    const bool bigws = ws_size >= base + ((size_t)16 << 20);
    float* xT = bigws ? (float*)(p + base) : (float*)d_ws;

    prep_kernel<<<bigws ? 1536 : 1024, 256, 0, stream>>>(x, cb, Apk, Bpk, esq, xT);
    mfma_dist_kernel<<<dim3(32, 16), 512, 0, stream>>>(Apk, Bpk, esq, cand);
    if (!bigws) transx_kernel<<<dim3(Bb, 32), 256, 0, stream>>>(x, xT);
    selres_kernel<<<Mm, 256, 0, stream>>>(cand, xT, cb, esq, fidx);
    gather_kernel<<<dim3(Bb, Dd / 64), 256, 0, stream>>>(fidx, vals, out);
}

// Round 5
// 180.619 us; speedup vs baseline: 1.0648x; 1.0648x over previous
//
#include <hip/hip_runtime.h>
#include <cstdint>

// VectorQuantizer: x[16,1024,16,16] f32, codebook[1,8192,1024], values[1,8192,1024]
// Round 12 (first HW-verified round: r11 passed, absmax 0.0, total 192.3 us,
// dist 64.0 us / MfmaUtil 21% / VALUBusy 39% / 0 bank conflicts).
// This round: (a) dist epilogue on 32-bit keys (score_bits&~0x3F | col6) --
// halves the bpermute/merge cost of the top-2 network; expanded to the same
// u64 (score<<32)|global_col at the cand write so selres is untouched.
// (b) prep: xT write fused into the Apk branch (x read once, 512 fewer blocks).
// Screening is i8 (s=24, exact integer dot); exact fp32 rescore of top-4.

constexpr int Dd = 1024;   // feature dim (GEMM K)
constexpr int Nn = 256;    // tokens per batch
constexpr int Bb = 16;     // batch
constexpr int Kk = 8192;   // codes (GEMM N)
constexpr int Mm = 4096;   // tokens (GEMM M)
constexpr int STAGES = Dd / 64;     // 16 x 64B K-chunks (kb index)
constexpr int NITER = STAGES / 2;   // 8 main-loop iterations, 128B K per iter
constexpr int NCHUNK = Kk / 64;     // 128 chunks of 64 codes
constexpr int NCAND = NCHUNK * 2;   // 256 candidates per token
constexpr float QS = 24.0f;         // quant scale
constexpr float SC2 = 2.0f / (QS * QS);

typedef __attribute__((ext_vector_type(4))) int vi4;       // 16 i8 = 4 VGPRs
typedef unsigned long long u64;
typedef unsigned char uchar;

__device__ __forceinline__ void gload16(const void* g, void* l) {
    // async global->LDS; lds dest = wave-uniform base + lane*16 (verified r2-r5)
    __builtin_amdgcn_global_load_lds((const __attribute__((address_space(1))) uint32_t*)g,
                                     (__attribute__((address_space(3))) uint32_t*)l, 16, 0, 0);
}

__device__ __forceinline__ void mm2u(uint32_t& a, uint32_t& b) {  // sort pair asc
    uint32_t lo = a < b ? a : b;
    uint32_t hi = a < b ? b : a;
    a = lo; b = hi;
}
// merge sorted pairs: (a1,a2) <- top-2 (smallest) of {a1,a2,b1,b2}
__device__ __forceinline__ void merge2u(uint32_t& a1, uint32_t& a2, uint32_t b1,
                                        uint32_t b2) {
    uint32_t t1 = a1 < b1 ? a1 : b1;
    uint32_t hi = a1 < b1 ? b1 : a1;
    uint32_t l2 = a2 < b2 ? a2 : b2;
    a2 = hi < l2 ? hi : l2;
    a1 = t1;
}

__device__ __forceinline__ int q8(float v) {  // round-to-nearest, clamp [-127,127]
    int qi = (int)rintf(v * QS);
    qi = qi > 127 ? 127 : (qi < -127 ? -127 : qi);
    return qi & 0xFF;
}
__device__ __forceinline__ int pk4i(float a, float b, float c, float d) {
    return q8(a) | (q8(b) << 8) | (q8(c) << 16) | (q8(d) << 24);
}

// Fragment-order packed layout (A and B identical; verified-symmetric for the
// 16x16 family): P[(g*16 + kb)*64 + lane]*16B, g = row>>4, kb = k>>6,
// lane = (row&15) | (q<<4), q = (k>>4)&3, byte j = k&15.

// ---------- prep ----------
// grid 1024: [0,512) cb->Bpk + esq; [512,1024) x->Apk (+xT when non-null)
__global__ __launch_bounds__(256) void prep_kernel(const float* __restrict__ x,
                                                   const float* __restrict__ cb,
                                                   uchar* __restrict__ Apk,
                                                   uchar* __restrict__ Bpk,
                                                   float* __restrict__ esq,
                                                   float* __restrict__ xT) {
    const int tid = threadIdx.x;
    if (blockIdx.x < 512) {  // codebook: 16 codes/block; thread=(rl 4b hi, seg 4b lo)
        const int rl = tid >> 4, seg = tid & 15;   // seg == kb
        const int code = blockIdx.x * 16 + rl;
        const float* src = cb + (size_t)code * Dd + seg * 64;
        float v[64];
        float ss = 0.f;
#pragma unroll
        for (int j = 0; j < 64; j += 4) {
            float4 f = *(const float4*)&src[j];
            v[j] = f.x; v[j + 1] = f.y; v[j + 2] = f.z; v[j + 3] = f.w;
            ss += f.x * f.x + f.y * f.y + f.z * f.z + f.w * f.w;
        }
#pragma unroll
        for (int off = 8; off; off >>= 1) ss += __shfl_down(ss, off, 16);
        if (seg == 0) esq[code] = ss;
        const int g = code >> 4, rlane = code & 15;
#pragma unroll
        for (int q = 0; q < 4; ++q) {
            int o[4];
#pragma unroll
            for (int w4 = 0; w4 < 4; ++w4) {
                const int j = q * 16 + w4 * 4;
                o[w4] = pk4i(v[j], v[j + 1], v[j + 2], v[j + 3]);
            }
            *(uint4*)&Bpk[((size_t)(g * 16 + seg) * 64 + (rlane | (q << 4))) * 16] =
                *(const uint4*)o;
        }
    } else {  // x -> Apk (+ xT): block=(b, d-chunk of 32), thread=n
        const int bb = blockIdx.x - 512;
        const int b = bb >> 5, d0 = (bb & 31) * 32, n = tid;
        const int t = b * 256 + n;
        const float* xb = x + (size_t)b * Dd * Nn + n;
        const int g = t >> 4, rlane = t & 15, kb = d0 >> 6, qbase = (d0 & 32) >> 4;
        float v[32];
#pragma unroll
        for (int jj = 0; jj < 32; ++jj) v[jj] = xb[(size_t)(d0 + jj) * Nn];
#pragma unroll
        for (int h = 0; h < 2; ++h) {
            int o[4];
#pragma unroll
            for (int w4 = 0; w4 < 4; ++w4) {
                const int j = h * 16 + w4 * 4;
                o[w4] = pk4i(v[j], v[j + 1], v[j + 2], v[j + 3]);
            }
            *(uint4*)&Apk[((size_t)(g * 16 + kb) * 64 + (rlane | ((qbase + h) << 4))) * 16] =
                *(const uint4*)o;
        }
        if (xT) {  // bigws only: write the already-loaded slice to xT
            float* row = xT + (size_t)t * Dd + d0;
#pragma unroll
            for (int jj = 0; jj < 32; jj += 4) {
                float4 f;
                f.x = v[jj]; f.y = v[jj + 1]; f.z = v[jj + 2]; f.w = v[jj + 3];
                *(float4*)&row[jj] = f;
            }
        }
    }
}

// ---------- x -> xT fp32 (fallback path, AFTER dist; aliases Apk/Bpk region) ----------
__global__ __launch_bounds__(256) void transx_kernel(const float* __restrict__ x,
                                                     float* __restrict__ xT) {
    const int n = threadIdx.x, b = blockIdx.x, d0 = blockIdx.y * 32;
    const float* xb = x + (size_t)b * Dd * Nn + n;
    float* row = xT + (size_t)(b * Nn + n) * Dd + d0;
#pragma unroll
    for (int jj = 0; jj < 8; ++jj) {
        float4 v;
        v.x = xb[(size_t)(d0 + jj * 4 + 0) * Nn];
        v.y = xb[(size_t)(d0 + jj * 4 + 1) * Nn];
        v.z = xb[(size_t)(d0 + jj * 4 + 2) * Nn];
        v.w = xb[(size_t)(d0 + jj * 4 + 3) * Nn];
        *(float4*)&row[jj * 4] = v;
    }
}

// ---------- i8 MFMA distance: 256x256 tile, counted-vmcnt phase schedule ----------
// grid (32, 16), 512 threads = 8 waves (wm in [0,2), wn in [0,4)).
// Wave owns a 128x64 output tile = 8x4 fragments of 16x16x64 MFMA.
// LDS: double buffer x 2 K-tiles(64B) x 16 groups x 1KB for A and for B = 128 KB.
// Main loop (7 iters, 128B K each) runs 2 phases; each phase:
//   issue 4 global_load_lds for iter i+1 -> s_waitcnt vmcnt(8) -> s_barrier ->
//   sched_barrier(0) -> 12 ds_read_b128 + 32 MFMA under setprio(1).
// Last iteration peeled: drain vmcnt 8->4->0, no dangling LDS-DMA at endpgm.
// Epilogue (r12): 32-bit keys (score_bits&~0x3F | col6) through the top-2 merge
// network (1 bpermute/step instead of 2, u32 min/cmp instead of u64); expanded
// to u64 (score<<32)|global_col at the cand write -- selres format unchanged,
// keys unique per token (distinct global cols). 6-bit score truncation is
// ~2^-18 relative -- negligible vs i8 quantization noise; top-4 exact rescore.
__global__ __launch_bounds__(512, 2) void mfma_dist_kernel(const uchar* __restrict__ Apk,
                                                           const uchar* __restrict__ Bpk,
                                                           const float* __restrict__ esq,
                                                           u64* __restrict__ cand) {
    __shared__ uchar As[2 * 2 * 16 * 1024];  // [buf][kt][group][1KB]
    __shared__ uchar Bs[2 * 2 * 16 * 1024];

    const int tid = threadIdx.x, lane = tid & 63, w = tid >> 6;
    const int wm = w >> 2, wn = w & 3;
    const int nBase = blockIdx.x * 256, mBase = blockIdx.y * 256;
    const int gA = blockIdx.y * 16, gB = blockIdx.x * 16;  // global 16-row group bases

    vi4 acc[8][4];
#pragma unroll
    for (int i = 0; i < 8; ++i)
#pragma unroll
        for (int j = 0; j < 4; ++j) acc[i][j] = (vi4)0;

    // Staging assignment: waves 0-3 stage A groups (w&3)*4..+3, waves 4-7 stage B.
    const uchar* gmat = (w < 4) ? Apk : Bpk;
    const int gBase = ((w < 4) ? gA : gB) + (w & 3) * 4;
    const uchar* gsrc = gmat + (size_t)gBase * 16384 + (size_t)lane * 16;
    uchar* swave = ((w < 4) ? As : Bs) + (w & 3) * 4096;  // + buf*32768 + kt*16384 + r*1024

    auto compute = [&](int buf, int kt) {
        __builtin_amdgcn_s_setprio(1);
        const uchar* ab = As + buf * 32768 + kt * 16384;
        const uchar* bb = Bs + buf * 32768 + kt * 16384;
        vi4 af[8], bf[4];
#pragma unroll
        for (int mi = 0; mi < 8; ++mi)
            af[mi] = *(const vi4*)&ab[((wm * 8 + mi) * 64 + lane) * 16];
#pragma unroll
        for (int ni = 0; ni < 4; ++ni)
            bf[ni] = *(const vi4*)&bb[((wn * 4 + ni) * 64 + lane) * 16];
#pragma unroll
        for (int mi = 0; mi < 8; ++mi)
#pragma unroll
            for (int ni = 0; ni < 4; ++ni)
                acc[mi][ni] = __builtin_amdgcn_mfma_i32_16x16x64_i8(
                    af[mi], bf[ni], acc[mi][ni], 0, 0, 0);
        __builtin_amdgcn_s_setprio(0);
    };

    // prologue: stage iter 0 (kb = 0 for kt0, kb = 1 for kt1) into buf 0
#pragma unroll
    for (int kt = 0; kt < 2; ++kt)
#pragma unroll
        for (int r = 0; r < 4; ++r)
            gload16(gsrc + (size_t)(r * 16 + kt) * 1024, swave + kt * 16384 + r * 1024);

    for (int i = 0; i < NITER - 1; ++i) {
        const int buf = i & 1;
#pragma unroll
        for (int kt = 0; kt < 2; ++kt) {
            // issue next-iter loads for this kt into buf^1
            const int kbn = 2 * i + 2 + kt;
            uchar* ldst = swave + (buf ^ 1) * 32768 + kt * 16384;
#pragma unroll
            for (int r = 0; r < 4; ++r)
                gload16(gsrc + (size_t)(r * 16 + kbn) * 1024, ldst + r * 1024);

            asm volatile("s_waitcnt vmcnt(8)" ::: "memory");  // publish iter i, kt
            __builtin_amdgcn_s_barrier();
            __builtin_amdgcn_sched_barrier(0);  // pin ds_reads behind the barrier
            compute(buf, kt);
        }
    }
    // peeled last iteration (buf = 1): no prefetch, explicit drain 8 -> 4 -> 0
    asm volatile("s_waitcnt vmcnt(4)" ::: "memory");
    __builtin_amdgcn_s_barrier();
    __builtin_amdgcn_sched_barrier(0);
    compute(1, 0);
    asm volatile("s_waitcnt vmcnt(0)" ::: "memory");
    __builtin_amdgcn_s_barrier();
    __builtin_amdgcn_sched_barrier(0);
    compute(1, 1);

    // Epilogue. C/D: col = lane&15 (+ni*16), row = (lane>>4)*4 + reg.
    // score = max(esq - (2/s^2)*dot, 0) >= 0 -> raw bits order = float order.
    // 32-bit key = (score_bits & ~0x3F) | (ni*16 | lane&15).
    const int chunk = blockIdx.x * 4 + wn;
    const uint32_t cbase = (uint32_t)(nBase + wn * 64);
    float e4[4];
#pragma unroll
    for (int ni = 0; ni < 4; ++ni) e4[ni] = esq[cbase + ni * 16 + (lane & 15)];
#pragma unroll
    for (int mi = 0; mi < 8; ++mi) {
#pragma unroll
        for (int reg = 0; reg < 4; ++reg) {
            uint32_t p[4];
#pragma unroll
            for (int ni = 0; ni < 4; ++ni) {
                float s = fmaxf(fmaf(-SC2, (float)acc[mi][ni][reg], e4[ni]), 0.f);
                p[ni] = (__float_as_uint(s) & 0xFFFFFFC0u) |
                        (uint32_t)(ni * 16 + (lane & 15));
            }
            mm2u(p[0], p[1]); mm2u(p[2], p[3]);
            merge2u(p[0], p[1], p[2], p[3]);
            uint32_t t1 = p[0], t2 = p[1];
#pragma unroll
            for (int d = 1; d < 16; d <<= 1) {
                uint32_t o1 = __shfl_xor(t1, d, 64);
                uint32_t o2 = __shfl_xor(t2, d, 64);
                merge2u(t1, t2, o1, o2);
            }
            if ((lane & 15) == 0) {
                const int t = mBase + wm * 128 + mi * 16 + (lane >> 4) * 4 + reg;
                cand[(size_t)t * NCAND + chunk * 2 + 0] =
                    ((u64)(t1 & 0xFFFFFFC0u) << 32) | (cbase + (t1 & 63u));
                cand[(size_t)t * NCAND + chunk * 2 + 1] =
                    ((u64)(t2 & 0xFFFFFFC0u) << 32) | (cbase + (t2 & 63u));
            }
        }
    }
}

// ---------- fused select(top-4 of 256) + exact fp32 rescore ----------
__global__ __launch_bounds__(256) void selres_kernel(const u64* __restrict__ cand,
                                                     const float* __restrict__ xT,
                                                     const float* __restrict__ cb,
                                                     const float* __restrict__ esq,
                                                     int* __restrict__ fidx) {
    __shared__ u64 wtop[4][4];
    __shared__ int cs[4];
    __shared__ float red[4][4];
    const int t = blockIdx.x, tid = threadIdx.x, lane = tid & 63, w = tid >> 6;
    u64 v = cand[(size_t)t * NCAND + tid];
#pragma unroll
    for (int rd = 0; rd < 4; ++rd) {  // per-wave top-4
        u64 m = v;
#pragma unroll
        for (int d = 32; d; d >>= 1) {
            u64 o = __shfl_xor(m, d, 64);
            m = m < o ? m : o;
        }
        if (lane == 0) wtop[w][rd] = m;
        if (v == m) v = ~0ULL;  // packed keys unique per token
    }
    __syncthreads();
    if (tid == 0) {  // merge 16 -> global top-4
        u64 a[16];
#pragma unroll
        for (int i = 0; i < 16; ++i) a[i] = wtop[i >> 2][i & 3];
#pragma unroll
        for (int rd = 0; rd < 4; ++rd) {
            int bi = 0;
            u64 m = a[0];
#pragma unroll
            for (int i = 1; i < 16; ++i)
                if (a[i] < m) { m = a[i]; bi = i; }
            cs[rd] = (int)(uint32_t)m;
            a[bi] = ~0ULL;
        }
    }
    __syncthreads();
    int c[4];
#pragma unroll
    for (int j = 0; j < 4; ++j) c[j] = cs[j];
    float4 xv = *(const float4*)&xT[(size_t)t * Dd + tid * 4];
    float part[4];
#pragma unroll
    for (int cc = 0; cc < 4; ++cc) {
        float4 wv = *(const float4*)&cb[(size_t)c[cc] * Dd + tid * 4];
        part[cc] = xv.x * wv.x + xv.y * wv.y + xv.z * wv.z + xv.w * wv.w;
    }
#pragma unroll
    for (int cc = 0; cc < 4; ++cc)
#pragma unroll
        for (int off = 32; off; off >>= 1) part[cc] += __shfl_down(part[cc], off, 64);
    if ((tid & 63) == 0)
#pragma unroll
        for (int cc = 0; cc < 4; ++cc) red[tid >> 6][cc] = part[cc];
    __syncthreads();
    if (tid == 0) {
        float bs = 1e30f;
        int bi = 0x7FFFFFFF;
#pragma unroll
        for (int cc = 0; cc < 4; ++cc) {
            float cross = red[0][cc] + red[1][cc] + red[2][cc] + red[3][cc];
            float s = fmaf(-2.f, cross, esq[c[cc]]);
            if (s < bs || (s == bs && c[cc] < bi)) { bs = s; bi = c[cc]; }
        }
        fidx[t] = bi;
    }
}

// ---------- gather values -> out ----------
__global__ __launch_bounds__(256) void gather_kernel(const int* __restrict__ fidx,
                                                     const float* __restrict__ values,
                                                     float* __restrict__ out) {
    const int n = threadIdx.x, b = blockIdx.x, dc = blockIdx.y;
    const int row = fidx[b * Nn + n];
    const float* src = values + (size_t)row * Dd + dc * 64;
    float* dst = out + (size_t)b * Dd * Nn + (size_t)dc * 64 * Nn + n;
#pragma unroll
    for (int j = 0; j < 64; j += 4) {
        float4 v = *(const float4*)(src + j);
        dst[(j + 0) * Nn] = v.x;
        dst[(j + 1) * Nn] = v.y;
        dst[(j + 2) * Nn] = v.z;
        dst[(j + 3) * Nn] = v.w;
    }
}

extern "C" void kernel_launch(void* const* d_in, const int* in_sizes, int n_in,
                              void* d_out, int out_size, void* d_ws, size_t ws_size,
                              hipStream_t stream) {
    const float* x = (const float*)d_in[0];
    const float* cb = (const float*)d_in[1];
    const float* vals = (const float*)d_in[2];
    float* out = (float*)d_out;

    // ws: [Apk 4M][Bpk 8M][pad->16M][esq 32K][cand 8M][fidx 16K] = 24.28 MB.
    // bigws: xT gets its own 16 MB after that (40.3 MB) and prep fills it;
    // else xT aliases the first 16 MB and is filled post-dist by transx.
    char* p = (char*)d_ws;
    uchar* Apk = (uchar*)p;
    uchar* Bpk = (uchar*)(p + ((size_t)4 << 20));
    float* esq = (float*)(p + ((size_t)16 << 20));
    u64* cand = (u64*)(p + ((size_t)16 << 20) + Kk * 4);
    int* fidx = (int*)(p + ((size_t)16 << 20) + Kk * 4 + (size_t)Mm * NCAND * 8);
    const size_t base = ((size_t)16 << 20) + Kk * 4 + (size_t)Mm * NCAND * 8 + Mm * 4;
    const bool bigws = ws_size >= base + ((size_t)16 << 20);
    float* xT = bigws ? (float*)(p + base) : (float*)d_ws;

    prep_kernel<<<1024, 256, 0, stream>>>(x, cb, Apk, Bpk, esq,
                                          bigws ? xT : nullptr);
    mfma_dist_kernel<<<dim3(32, 16), 512, 0, stream>>>(Apk, Bpk, esq, cand);
    if (!bigws) transx_kernel<<<dim3(Bb, 32), 256, 0, stream>>>(x, xT);
    selres_kernel<<<Mm, 256, 0, stream>>>(cand, xT, cb, esq, fidx);
    gather_kernel<<<dim3(Bb, Dd / 64), 256, 0, stream>>>(fidx, vals, out);
}

// Round 7
// 172.879 us; speedup vs baseline: 1.1124x; 1.0448x over previous
//
#include <hip/hip_runtime.h>
#include <cstdint>

// VectorQuantizer: x[16,1024,16,16] f32, codebook[1,8192,1024], values[1,8192,1024]
// Round 14 == Round 13 (broker timeout; DPP change desk-audited, held stable).
// r12 HW baseline: passed, absmax 0.0, total 180.6 us, dist 48.2 us.
// r13 change under test: shuffle->DPP transport in reduction networks
// (bit-identical): dist epilogue 8 ds_bpermute -> 8 v_mov_dpp row_ror (1,2,4,8
// disjoint-window rotate-merge); selres rounds ror 1,2,4,8 via DPP + shfl_xor
// 16/32. Main-loop sync structure (HW-verified r11/r12) untouched.

constexpr int Dd = 1024;   // feature dim (GEMM K)
constexpr int Nn = 256;    // tokens per batch
constexpr int Bb = 16;     // batch
constexpr int Kk = 8192;   // codes (GEMM N)
constexpr int Mm = 4096;   // tokens (GEMM M)
constexpr int STAGES = Dd / 64;     // 16 x 64B K-chunks (kb index)
constexpr int NITER = STAGES / 2;   // 8 main-loop iterations, 128B K per iter
constexpr int NCHUNK = Kk / 64;     // 128 chunks of 64 codes
constexpr int NCAND = NCHUNK * 2;   // 256 candidates per token
constexpr float QS = 24.0f;         // quant scale
constexpr float SC2 = 2.0f / (QS * QS);

typedef __attribute__((ext_vector_type(4))) int vi4;       // 16 i8 = 4 VGPRs
typedef unsigned long long u64;
typedef unsigned char uchar;

__device__ __forceinline__ void gload16(const void* g, void* l) {
    // async global->LDS; lds dest = wave-uniform base + lane*16 (verified r2-r5)
    __builtin_amdgcn_global_load_lds((const __attribute__((address_space(1))) uint32_t*)g,
                                     (__attribute__((address_space(3))) uint32_t*)l, 16, 0, 0);
}

// DPP row_ror:N within 16-lane rows (VALU-rate cross-lane; all lanes active).
template <int CTRL>
__device__ __forceinline__ uint32_t rot16(uint32_t v) {
    return (uint32_t)__builtin_amdgcn_update_dpp(0, (int)v, CTRL, 0xF, 0xF, true);
}
template <int CTRL>
__device__ __forceinline__ u64 rot16_64(u64 v) {
    uint32_t lo = rot16<CTRL>((uint32_t)v);
    uint32_t hi = rot16<CTRL>((uint32_t)(v >> 32));
    return ((u64)hi << 32) | lo;
}

__device__ __forceinline__ void mm2u(uint32_t& a, uint32_t& b) {  // sort pair asc
    uint32_t lo = a < b ? a : b;
    uint32_t hi = a < b ? b : a;
    a = lo; b = hi;
}
// merge sorted pairs: (a1,a2) <- top-2 (smallest) of {a1,a2,b1,b2}
__device__ __forceinline__ void merge2u(uint32_t& a1, uint32_t& a2, uint32_t b1,
                                        uint32_t b2) {
    uint32_t t1 = a1 < b1 ? a1 : b1;
    uint32_t hi = a1 < b1 ? b1 : a1;
    uint32_t l2 = a2 < b2 ? a2 : b2;
    a2 = hi < l2 ? hi : l2;
    a1 = t1;
}

__device__ __forceinline__ int q8(float v) {  // round-to-nearest, clamp [-127,127]
    int qi = (int)rintf(v * QS);
    qi = qi > 127 ? 127 : (qi < -127 ? -127 : qi);
    return qi & 0xFF;
}
__device__ __forceinline__ int pk4i(float a, float b, float c, float d) {
    return q8(a) | (q8(b) << 8) | (q8(c) << 16) | (q8(d) << 24);
}

// Fragment-order packed layout (A and B identical; verified-symmetric for the
// 16x16 family): P[(g*16 + kb)*64 + lane]*16B, g = row>>4, kb = k>>6,
// lane = (row&15) | (q<<4), q = (k>>4)&3, byte j = k&15.

// ---------- prep ----------
// grid 1024: [0,512) cb->Bpk + esq; [512,1024) x->Apk (+xT when non-null)
__global__ __launch_bounds__(256) void prep_kernel(const float* __restrict__ x,
                                                   const float* __restrict__ cb,
                                                   uchar* __restrict__ Apk,
                                                   uchar* __restrict__ Bpk,
                                                   float* __restrict__ esq,
                                                   float* __restrict__ xT) {
    const int tid = threadIdx.x;
    if (blockIdx.x < 512) {  // codebook: 16 codes/block; thread=(rl 4b hi, seg 4b lo)
        const int rl = tid >> 4, seg = tid & 15;   // seg == kb
        const int code = blockIdx.x * 16 + rl;
        const float* src = cb + (size_t)code * Dd + seg * 64;
        float v[64];
        float ss = 0.f;
#pragma unroll
        for (int j = 0; j < 64; j += 4) {
            float4 f = *(const float4*)&src[j];
            v[j] = f.x; v[j + 1] = f.y; v[j + 2] = f.z; v[j + 3] = f.w;
            ss += f.x * f.x + f.y * f.y + f.z * f.z + f.w * f.w;
        }
#pragma unroll
        for (int off = 8; off; off >>= 1) ss += __shfl_down(ss, off, 16);
        if (seg == 0) esq[code] = ss;
        const int g = code >> 4, rlane = code & 15;
#pragma unroll
        for (int q = 0; q < 4; ++q) {
            int o[4];
#pragma unroll
            for (int w4 = 0; w4 < 4; ++w4) {
                const int j = q * 16 + w4 * 4;
                o[w4] = pk4i(v[j], v[j + 1], v[j + 2], v[j + 3]);
            }
            *(uint4*)&Bpk[((size_t)(g * 16 + seg) * 64 + (rlane | (q << 4))) * 16] =
                *(const uint4*)o;
        }
    } else {  // x -> Apk (+ xT): block=(b, d-chunk of 32), thread=n
        const int bb = blockIdx.x - 512;
        const int b = bb >> 5, d0 = (bb & 31) * 32, n = tid;
        const int t = b * 256 + n;
        const float* xb = x + (size_t)b * Dd * Nn + n;
        const int g = t >> 4, rlane = t & 15, kb = d0 >> 6, qbase = (d0 & 32) >> 4;
        float v[32];
#pragma unroll
        for (int jj = 0; jj < 32; ++jj) v[jj] = xb[(size_t)(d0 + jj) * Nn];
#pragma unroll
        for (int h = 0; h < 2; ++h) {
            int o[4];
#pragma unroll
            for (int w4 = 0; w4 < 4; ++w4) {
                const int j = h * 16 + w4 * 4;
                o[w4] = pk4i(v[j], v[j + 1], v[j + 2], v[j + 3]);
            }
            *(uint4*)&Apk[((size_t)(g * 16 + kb) * 64 + (rlane | ((qbase + h) << 4))) * 16] =
                *(const uint4*)o;
        }
        if (xT) {  // bigws only: write the already-loaded slice to xT
            float* row = xT + (size_t)t * Dd + d0;
#pragma unroll
            for (int jj = 0; jj < 32; jj += 4) {
                float4 f;
                f.x = v[jj]; f.y = v[jj + 1]; f.z = v[jj + 2]; f.w = v[jj + 3];
                *(float4*)&row[jj] = f;
            }
        }
    }
}

// ---------- x -> xT fp32 (fallback path, AFTER dist; aliases Apk/Bpk region) ----------
__global__ __launch_bounds__(256) void transx_kernel(const float* __restrict__ x,
                                                     float* __restrict__ xT) {
    const int n = threadIdx.x, b = blockIdx.x, d0 = blockIdx.y * 32;
    const float* xb = x + (size_t)b * Dd * Nn + n;
    float* row = xT + (size_t)(b * Nn + n) * Dd + d0;
#pragma unroll
    for (int jj = 0; jj < 8; ++jj) {
        float4 v;
        v.x = xb[(size_t)(d0 + jj * 4 + 0) * Nn];
        v.y = xb[(size_t)(d0 + jj * 4 + 1) * Nn];
        v.z = xb[(size_t)(d0 + jj * 4 + 2) * Nn];
        v.w = xb[(size_t)(d0 + jj * 4 + 3) * Nn];
        *(float4*)&row[jj * 4] = v;
    }
}

// ---------- i8 MFMA distance: 256x256 tile, counted-vmcnt phase schedule ----------
// grid (32, 16), 512 threads = 8 waves (wm in [0,2), wn in [0,4)).
// Wave owns a 128x64 output tile = 8x4 fragments of 16x16x64 MFMA.
// LDS: double buffer x 2 K-tiles(64B) x 16 groups x 1KB for A and for B = 128 KB.
// Main loop (7 iters, 128B K each) runs 2 phases; each phase:
//   issue 4 global_load_lds for iter i+1 -> s_waitcnt vmcnt(8) -> s_barrier ->
//   sched_barrier(0) -> 12 ds_read_b128 + 32 MFMA under setprio(1).
// Last iteration peeled: drain vmcnt 8->4->0, no dangling LDS-DMA at endpgm.
// Epilogue (r13): 32-bit keys through a DPP row_ror merge network -- rotation
// by 1,2,4,8 within each 16-lane row gives disjoint windows (== xor-butterfly,
// bit-identical) at VALU rate instead of 8 ds_bpermute chains per output.
__global__ __launch_bounds__(512, 2) void mfma_dist_kernel(const uchar* __restrict__ Apk,
                                                           const uchar* __restrict__ Bpk,
                                                           const float* __restrict__ esq,
                                                           u64* __restrict__ cand) {
    __shared__ uchar As[2 * 2 * 16 * 1024];  // [buf][kt][group][1KB]
    __shared__ uchar Bs[2 * 2 * 16 * 1024];

    const int tid = threadIdx.x, lane = tid & 63, w = tid >> 6;
    const int wm = w >> 2, wn = w & 3;
    const int nBase = blockIdx.x * 256, mBase = blockIdx.y * 256;
    const int gA = blockIdx.y * 16, gB = blockIdx.x * 16;  // global 16-row group bases

    vi4 acc[8][4];
#pragma unroll
    for (int i = 0; i < 8; ++i)
#pragma unroll
        for (int j = 0; j < 4; ++j) acc[i][j] = (vi4)0;

    // Staging assignment: waves 0-3 stage A groups (w&3)*4..+3, waves 4-7 stage B.
    const uchar* gmat = (w < 4) ? Apk : Bpk;
    const int gBase = ((w < 4) ? gA : gB) + (w & 3) * 4;
    const uchar* gsrc = gmat + (size_t)gBase * 16384 + (size_t)lane * 16;
    uchar* swave = ((w < 4) ? As : Bs) + (w & 3) * 4096;  // + buf*32768 + kt*16384 + r*1024

    auto compute = [&](int buf, int kt) {
        __builtin_amdgcn_s_setprio(1);
        const uchar* ab = As + buf * 32768 + kt * 16384;
        const uchar* bb = Bs + buf * 32768 + kt * 16384;
        vi4 af[8], bf[4];
#pragma unroll
        for (int mi = 0; mi < 8; ++mi)
            af[mi] = *(const vi4*)&ab[((wm * 8 + mi) * 64 + lane) * 16];
#pragma unroll
        for (int ni = 0; ni < 4; ++ni)
            bf[ni] = *(const vi4*)&bb[((wn * 4 + ni) * 64 + lane) * 16];
#pragma unroll
        for (int mi = 0; mi < 8; ++mi)
#pragma unroll
            for (int ni = 0; ni < 4; ++ni)
                acc[mi][ni] = __builtin_amdgcn_mfma_i32_16x16x64_i8(
                    af[mi], bf[ni], acc[mi][ni], 0, 0, 0);
        __builtin_amdgcn_s_setprio(0);
    };

    // prologue: stage iter 0 (kb = 0 for kt0, kb = 1 for kt1) into buf 0
#pragma unroll
    for (int kt = 0; kt < 2; ++kt)
#pragma unroll
        for (int r = 0; r < 4; ++r)
            gload16(gsrc + (size_t)(r * 16 + kt) * 1024, swave + kt * 16384 + r * 1024);

    for (int i = 0; i < NITER - 1; ++i) {
        const int buf = i & 1;
#pragma unroll
        for (int kt = 0; kt < 2; ++kt) {
            // issue next-iter loads for this kt into buf^1
            const int kbn = 2 * i + 2 + kt;
            uchar* ldst = swave + (buf ^ 1) * 32768 + kt * 16384;
#pragma unroll
            for (int r = 0; r < 4; ++r)
                gload16(gsrc + (size_t)(r * 16 + kbn) * 1024, ldst + r * 1024);

            asm volatile("s_waitcnt vmcnt(8)" ::: "memory");  // publish iter i, kt
            __builtin_amdgcn_s_barrier();
            __builtin_amdgcn_sched_barrier(0);  // pin ds_reads behind the barrier
            compute(buf, kt);
        }
    }
    // peeled last iteration (buf = 1): no prefetch, explicit drain 8 -> 4 -> 0
    asm volatile("s_waitcnt vmcnt(4)" ::: "memory");
    __builtin_amdgcn_s_barrier();
    __builtin_amdgcn_sched_barrier(0);
    compute(1, 0);
    asm volatile("s_waitcnt vmcnt(0)" ::: "memory");
    __builtin_amdgcn_s_barrier();
    __builtin_amdgcn_sched_barrier(0);
    compute(1, 1);

    // Epilogue. C/D: col = lane&15 (+ni*16), row = (lane>>4)*4 + reg.
    // score = max(esq - (2/s^2)*dot, 0) >= 0 -> raw bits order = float order.
    // 32-bit key = (score_bits & ~0x3F) | (ni*16 | lane&15).
    const int chunk = blockIdx.x * 4 + wn;
    const uint32_t cbase = (uint32_t)(nBase + wn * 64);
    float e4[4];
#pragma unroll
    for (int ni = 0; ni < 4; ++ni) e4[ni] = esq[cbase + ni * 16 + (lane & 15)];
#pragma unroll
    for (int mi = 0; mi < 8; ++mi) {
#pragma unroll
        for (int reg = 0; reg < 4; ++reg) {
            uint32_t p[4];
#pragma unroll
            for (int ni = 0; ni < 4; ++ni) {
                float s = fmaxf(fmaf(-SC2, (float)acc[mi][ni][reg], e4[ni]), 0.f);
                p[ni] = (__float_as_uint(s) & 0xFFFFFFC0u) |
                        (uint32_t)(ni * 16 + (lane & 15));
            }
            mm2u(p[0], p[1]); mm2u(p[2], p[3]);
            merge2u(p[0], p[1], p[2], p[3]);
            uint32_t t1 = p[0], t2 = p[1];
            // DPP rotate-merge within the 16-lane row (disjoint windows 1,2,4,8)
            { uint32_t o1 = rot16<0x121>(t1), o2 = rot16<0x121>(t2);
              merge2u(t1, t2, o1, o2); }
            { uint32_t o1 = rot16<0x122>(t1), o2 = rot16<0x122>(t2);
              merge2u(t1, t2, o1, o2); }
            { uint32_t o1 = rot16<0x124>(t1), o2 = rot16<0x124>(t2);
              merge2u(t1, t2, o1, o2); }
            { uint32_t o1 = rot16<0x128>(t1), o2 = rot16<0x128>(t2);
              merge2u(t1, t2, o1, o2); }
            if ((lane & 15) == 0) {
                const int t = mBase + wm * 128 + mi * 16 + (lane >> 4) * 4 + reg;
                cand[(size_t)t * NCAND + chunk * 2 + 0] =
                    ((u64)(t1 & 0xFFFFFFC0u) << 32) | (cbase + (t1 & 63u));
                cand[(size_t)t * NCAND + chunk * 2 + 1] =
                    ((u64)(t2 & 0xFFFFFFC0u) << 32) | (cbase + (t2 & 63u));
            }
        }
    }
}

// ---------- fused select(top-4 of 256) + exact fp32 rescore ----------
__global__ __launch_bounds__(256) void selres_kernel(const u64* __restrict__ cand,
                                                     const float* __restrict__ xT,
                                                     const float* __restrict__ cb,
                                                     const float* __restrict__ esq,
                                                     int* __restrict__ fidx) {
    __shared__ u64 wtop[4][4];
    __shared__ int cs[4];
    __shared__ float red[4][4];
    const int t = blockIdx.x, tid = threadIdx.x, lane = tid & 63, w = tid >> 6;
    u64 v = cand[(size_t)t * NCAND + tid];
#pragma unroll
    for (int rd = 0; rd < 4; ++rd) {  // per-wave top-4 (u64 min, bit-identical)
        u64 m = v;
        { u64 o = rot16_64<0x121>(m); m = m < o ? m : o; }
        { u64 o = rot16_64<0x122>(m); m = m < o ? m : o; }
        { u64 o = rot16_64<0x124>(m); m = m < o ? m : o; }
        { u64 o = rot16_64<0x128>(m); m = m < o ? m : o; }
        { u64 o = __shfl_xor(m, 16, 64); m = m < o ? m : o; }
        { u64 o = __shfl_xor(m, 32, 64); m = m < o ? m : o; }
        if (lane == 0) wtop[w][rd] = m;
        if (v == m) v = ~0ULL;  // packed keys unique per token
    }
    __syncthreads();
    if (tid == 0) {  // merge 16 -> global top-4
        u64 a[16];
#pragma unroll
        for (int i = 0; i < 16; ++i) a[i] = wtop[i >> 2][i & 3];
#pragma unroll
        for (int rd = 0; rd < 4; ++rd) {
            int bi = 0;
            u64 m = a[0];
#pragma unroll
            for (int i = 1; i < 16; ++i)
                if (a[i] < m) { m = a[i]; bi = i; }
            cs[rd] = (int)(uint32_t)m;
            a[bi] = ~0ULL;
        }
    }
    __syncthreads();
    int c[4];
#pragma unroll
    for (int j = 0; j < 4; ++j) c[j] = cs[j];
    float4 xv = *(const float4*)&xT[(size_t)t * Dd + tid * 4];
    float part[4];
#pragma unroll
    for (int cc = 0; cc < 4; ++cc) {
        float4 wv = *(const float4*)&cb[(size_t)c[cc] * Dd + tid * 4];
        part[cc] = xv.x * wv.x + xv.y * wv.y + xv.z * wv.z + xv.w * wv.w;
    }
#pragma unroll
    for (int cc = 0; cc < 4; ++cc)
#pragma unroll
        for (int off = 32; off; off >>= 1) part[cc] += __shfl_down(part[cc], off, 64);
    if ((tid & 63) == 0)
#pragma unroll
        for (int cc = 0; cc < 4; ++cc) red[tid >> 6][cc] = part[cc];
    __syncthreads();
    if (tid == 0) {
        float bs = 1e30f;
        int bi = 0x7FFFFFFF;
#pragma unroll
        for (int cc = 0; cc < 4; ++cc) {
            float cross = red[0][cc] + red[1][cc] + red[2][cc] + red[3][cc];
            float s = fmaf(-2.f, cross, esq[c[cc]]);
            if (s < bs || (s == bs && c[cc] < bi)) { bs = s; bi = c[cc]; }
        }
        fidx[t] = bi;
    }
}

// ---------- gather values -> out ----------
__global__ __launch_bounds__(256) void gather_kernel(const int* __restrict__ fidx,
                                                     const float* __restrict__ values,
                                                     float* __restrict__ out) {
    const int n = threadIdx.x, b = blockIdx.x, dc = blockIdx.y;
    const int row = fidx[b * Nn + n];
    const float* src = values + (size_t)row * Dd + dc * 64;
    float* dst = out + (size_t)b * Dd * Nn + (size_t)dc * 64 * Nn + n;
#pragma unroll
    for (int j = 0; j < 64; j += 4) {
        float4 v = *(const float4*)(src + j);
        dst[(j + 0) * Nn] = v.x;
        dst[(j + 1) * Nn] = v.y;
        dst[(j + 2) * Nn] = v.z;
        dst[(j + 3) * Nn] = v.w;
    }
}

extern "C" void kernel_launch(void* const* d_in, const int* in_sizes, int n_in,
                              void* d_out, int out_size, void* d_ws, size_t ws_size,
                              hipStream_t stream) {
    const float* x = (const float*)d_in[0];
    const float* cb = (const float*)d_in[1];
    const float* vals = (const float*)d_in[2];
    float* out = (float*)d_out;

    // ws: [Apk 4M][Bpk 8M][pad->16M][esq 32K][cand 8M][fidx 16K] = 24.28 MB.
    // bigws: xT gets its own 16 MB after that (40.3 MB) and prep fills it;
    // else xT aliases the first 16 MB and is filled post-dist by transx.
    char* p = (char*)d_ws;
    uchar* Apk = (uchar*)p;
    uchar* Bpk = (uchar*)(p + ((size_t)4 << 20));
    float* esq = (float*)(p + ((size_t)16 << 20));
    u64* cand = (u64*)(p + ((size_t)16 << 20) + Kk * 4);
    int* fidx = (int*)(p + ((size_t)16 << 20) + Kk * 4 + (size_t)Mm * NCAND * 8);
    const size_t base = ((size_t)16 << 20) + Kk * 4 + (size_t)Mm * NCAND * 8 + Mm * 4;
    const bool bigws = ws_size >= base + ((size_t)16 << 20);
    float* xT = bigws ? (float*)(p + base) : (float*)d_ws;

    prep_kernel<<<1024, 256, 0, stream>>>(x, cb, Apk, Bpk, esq,
                                          bigws ? xT : nullptr);
    mfma_dist_kernel<<<dim3(32, 16), 512, 0, stream>>>(Apk, Bpk, esq, cand);
    if (!bigws) transx_kernel<<<dim3(Bb, 32), 256, 0, stream>>>(x, xT);
    selres_kernel<<<Mm, 256, 0, stream>>>(cand, xT, cb, esq, fidx);
    gather_kernel<<<dim3(Bb, Dd / 64), 256, 0, stream>>>(fidx, vals, out);
}